// Round 6
// baseline (298.004 us; speedup 1.0000x reference)
//
#include <hip/hip_runtime.h>
#include <hip/hip_bf16.h>

#define Hh 50

typedef __attribute__((ext_vector_type(8))) short bf16x8;
typedef __attribute__((ext_vector_type(4))) short s16x4;
typedef __attribute__((ext_vector_type(4))) float f32x4;
typedef __attribute__((ext_vector_type(2))) float f32x2;

static __device__ __forceinline__ short b16(float x) {
    return __builtin_bit_cast(short, __float2bfloat16(x));
}
// convert 8 contiguous f32 to a bf16x8 MFMA fragment
static __device__ __forceinline__ bf16x8 cvt8(const float* p) {
    f32x4 a = *(const f32x4*)p;
    f32x4 b = *(const f32x4*)(p + 4);
    bf16x8 r;
    r[0] = b16(a[0]); r[1] = b16(a[1]); r[2] = b16(a[2]); r[3] = b16(a[3]);
    r[4] = b16(b[0]); r[5] = b16(b[1]); r[6] = b16(b[2]); r[7] = b16(b[3]);
    return r;
}

// ---------------- Kernel 0: wh_w f32 -> bf16 (row-major [256][256]) ----------------
__global__ __launch_bounds__(256) void k_prep(const float* __restrict__ w,
                                              short* __restrict__ o) {
    int i = ((int)blockIdx.x * 256 + threadIdx.x) * 4;
    f32x4 v = *(const f32x4*)(w + i);
    s16x4 r;
    r[0] = b16(v[0]); r[1] = b16(v[1]); r[2] = b16(v[2]); r[3] = b16(v[3]);
    *(s16x4*)(o + i) = r;
}

// ---------------- Kernel 1: wc_out[4096][256] (f32) = cur @ wc_w^T + wc_b ----------------
__global__ __launch_bounds__(64) void k_wc(const float* __restrict__ cur,
                                           const float* __restrict__ wcw,
                                           const float* __restrict__ wcb,
                                           float* __restrict__ out) {
    int l = threadIdx.x;
    int m0 = (int)(blockIdx.x >> 2) * 16;
    int ntb = (int)(blockIdx.x & 3) * 4;
    int lk = (l >> 4) * 8;

    bf16x8 Af[8];
#pragma unroll
    for (int k = 0; k < 8; k++)
        Af[k] = cvt8(cur + (size_t)(m0 + (l & 15)) * 256 + k * 32 + lk);

#pragma unroll
    for (int nt = 0; nt < 4; nt++) {
        int col = (ntb + nt) * 16 + (l & 15);
        f32x4 a = {0.f, 0.f, 0.f, 0.f};
#pragma unroll
        for (int k = 0; k < 8; k++) {
            bf16x8 Bf = cvt8(wcw + (size_t)col * 256 + k * 32 + lk);
            a = __builtin_amdgcn_mfma_f32_16x16x32_bf16(Af[k], Bf, a, 0, 0, 0);
        }
        float bias = wcb[col];
        int row = m0 + (l >> 4) * 4;
#pragma unroll
        for (int r = 0; r < 4; r++)
            out[(size_t)(row + r) * 256 + col] = a[r] + bias;
    }
}

// ---------------- Kernel 2: fused wh GEMM + sigmoid + qt dot + alpha*hist ----------------
// Block = (b, s0, s0+1), 512 threads = 8 waves. LDS rows interleaved: row = 2h + si.
// Wave w (0..6) owns m-tile w (16 rows) for ALL 256 cols: Af[8]=32 VGPR resident,
// B double-buffered (64 VGPR) from preconverted bf16 wh_w -> ~115 VGPR, no spill.
// Wave 7 (pure pad rows) skips the GEMM. 2 blocks/CU (LDS) x 8 waves = 4 waves/SIMD.
__global__ __launch_bounds__(512, 4)
void k_main(const float* __restrict__ hist,
            const float* __restrict__ wc_ws,
            const short* __restrict__ whb16,
            const float* __restrict__ whb,
            const float* __restrict__ qtw,
            const float* __restrict__ qtb,
            float* __restrict__ hsum_ws) {
    __shared__ __align__(16) char histA[112 * 512];   // swizzled bf16 [row][256]
    __shared__ float wcrow[512];                       // wc_out + wh_b, si=0/1
    __shared__ float qtl[256];
    __shared__ float alphaF[128];

    int tid = threadIdx.x;
    int l = tid & 63;
    int w = tid >> 6;
    int b = (int)(blockIdx.x >> 8);
    int s0 = (int)(blockIdx.x & 255) * 2;

    // stage hist rows (100 rows x 256 elems) into swizzled LDS as bf16
    for (int c = tid; c < 3200; c += 512) {
        int row = c >> 5;              // 0..99 = 2h+si
        int h = row >> 1, si = row & 1;
        bf16x8 v = cvt8(hist + ((size_t)(b * Hh + h) * 512 + (s0 + si)) * 256 + (c & 31) * 8);
        int off = row * 512 + (((c & 31) * 16) ^ ((row & 7) << 4));
        *(bf16x8*)(&histA[off]) = v;
    }
    // zero pad rows 100..111
    if (tid < 384) {
        int row = 100 + (tid >> 5);
        *(f32x4*)(&histA[row * 512 + (tid & 31) * 16]) = (f32x4){0.f, 0.f, 0.f, 0.f};
    }
    // combined bias tables: wcrow[si*256+o] = wc_out[s0+si][o] + wh_b[o]; qtl = qt_w
    wcrow[tid] = wc_ws[(size_t)(b * 512 + s0) * 256 + tid] + whb[tid & 255];
    if (tid < 256) qtl[tid] = qtw[tid];
    __syncthreads();

    if (w < 7) {
        int mt = w;
        // A fragments for this wave's m-tile, loaded once from LDS
        int arow = mt * 16 + (l & 15);
        bf16x8 Af[8];
#pragma unroll
        for (int k = 0; k < 8; k++) {
            int off = arow * 512 + (((k * 64) + (l >> 4) * 16) ^ ((arow & 7) << 4));
            Af[k] = *(const bf16x8*)(&histA[off]);
        }

        float pal[4] = {0.f, 0.f, 0.f, 0.f};
        const short* wp = whb16 + (l & 15) * 256 + (l >> 4) * 8;

        bf16x8 B0[8], B1[8];
        auto LD = [&](bf16x8 (&Bn)[8], int nt) {
#pragma unroll
            for (int k = 0; k < 8; k++)
                Bn[k] = *(const bf16x8*)(wp + nt * 4096 + k * 32);
        };
        auto STEP = [&](bf16x8 (&Bc)[8], int nt) {
            int o = nt * 16 + (l & 15);
            float qv = qtl[o];
            float wb0 = wcrow[o];
            float wb1 = wcrow[256 + o];
            f32x4 acc = {0.f, 0.f, 0.f, 0.f};
#pragma unroll
            for (int k = 0; k < 8; k++)
                acc = __builtin_amdgcn_mfma_f32_16x16x32_bf16(Af[k], Bc[k], acc, 0, 0, 0);
#pragma unroll
            for (int r = 0; r < 4; r++) {
                float v = acc[r] + ((r & 1) ? wb1 : wb0);
                float sg = __builtin_amdgcn_rcpf(1.0f + __expf(-v));
                pal[r] += qv * sg;
            }
        };

        LD(B0, 0);
#pragma unroll
        for (int np = 0; np < 8; np++) {
            int ntA = 2 * np, ntB = 2 * np + 1;
            LD(B1, ntB);
            STEP(B0, ntA);
            if (np < 7) LD(B0, ntA + 2);
            STEP(B1, ntB);
        }

        // alpha: reduce over the 16 lanes holding the 16 cols of each row-group
        float qtb0 = qtb[0];
#pragma unroll
        for (int r = 0; r < 4; r++) {
            float v = pal[r];
            v += __shfl_xor(v, 1);
            v += __shfl_xor(v, 2);
            v += __shfl_xor(v, 4);
            v += __shfl_xor(v, 8);
            if ((l & 15) == 0)
                alphaF[mt * 16 + (l >> 4) * 4 + r] = qtb0 + v;
        }
    }
    __syncthreads();

    // history_sum = sum_h alpha[row] * hist[row], from LDS; one f32 column/thread
    {
        int d = tid & 255;
        int si = tid >> 8;
        float a = 0.f;
#pragma unroll 2
        for (int h = 0; h < Hh; h++) {
            int row = 2 * h + si;
            unsigned short u = *(const unsigned short*)(&histA[row * 512 + ((d * 2) ^ ((row & 7) << 4))]);
            unsigned int x = ((unsigned int)u) << 16;
            a += alphaF[row] * __builtin_bit_cast(float, x);
        }
        hsum_ws[(size_t)(b * 512 + s0 + si) * 256 + d] = a;
    }
}

// ---------------- Kernel 3: out[4096][128] (f32) = [cur, hsum] @ wf_w^T + wf_b ----------------
__global__ __launch_bounds__(64) void k_wf(const float* __restrict__ cur,
                                           const float* __restrict__ hsum,
                                           const float* __restrict__ wfw,
                                           const float* __restrict__ wfb,
                                           float* __restrict__ out) {
    int l = threadIdx.x;
    int m0 = (int)(blockIdx.x >> 1) * 16;
    int ntb = (int)(blockIdx.x & 1) * 4;
    int lk = (l >> 4) * 8;

    f32x4 acc[4];
#pragma unroll
    for (int nt = 0; nt < 4; nt++) acc[nt] = (f32x4){0.f, 0.f, 0.f, 0.f};

#pragma unroll
    for (int k = 0; k < 16; k++) {
        int row = m0 + (l & 15);
        bf16x8 Af;
        if (k < 8)
            Af = cvt8(cur + (size_t)row * 256 + k * 32 + lk);
        else
            Af = cvt8(hsum + (size_t)row * 256 + (k - 8) * 32 + lk);
#pragma unroll
        for (int nt = 0; nt < 4; nt++) {
            int col = (ntb + nt) * 16 + (l & 15);
            bf16x8 Bf = cvt8(wfw + (size_t)col * 512 + k * 32 + lk);
            acc[nt] = __builtin_amdgcn_mfma_f32_16x16x32_bf16(Af, Bf, acc[nt], 0, 0, 0);
        }
    }
#pragma unroll
    for (int nt = 0; nt < 4; nt++) {
        int col = (ntb + nt) * 16 + (l & 15);
        float bias = wfb[col];
        int row = m0 + (l >> 4) * 4;
#pragma unroll
        for (int r = 0; r < 4; r++)
            out[(size_t)(row + r) * 128 + col] = acc[nt][r] + bias;
    }
}

extern "C" void kernel_launch(void* const* d_in, const int* in_sizes, int n_in,
                              void* d_out, int out_size, void* d_ws, size_t ws_size,
                              hipStream_t stream) {
    const float* hist = (const float*)d_in[0];
    const float* cur  = (const float*)d_in[1];
    const float* wc_w = (const float*)d_in[2];
    const float* wc_b = (const float*)d_in[3];
    const float* wh_w = (const float*)d_in[4];
    const float* wh_b = (const float*)d_in[5];
    const float* qt_w = (const float*)d_in[6];
    const float* qt_b = (const float*)d_in[7];
    const float* wf_w = (const float*)d_in[8];
    const float* wf_b = (const float*)d_in[9];

    float* wc_ws = (float*)d_ws;                                   // 4 MB
    float* hsum  = (float*)((char*)d_ws + ((size_t)4 << 20));      // 4 MB
    short* whb16 = (short*)((char*)d_ws + ((size_t)8 << 20));      // 128 KB

    k_prep<<<64, 256, 0, stream>>>(wh_w, whb16);
    k_wc<<<1024, 64, 0, stream>>>(cur, wc_w, wc_b, wc_ws);
    k_main<<<2048, 512, 0, stream>>>(hist, wc_ws, whb16, wh_b, qt_w, qt_b, hsum);
    k_wf<<<512, 64, 0, stream>>>(cur, hsum, wf_w, wf_b, (float*)d_out);
}

// Round 7
// 135.381 us; speedup vs baseline: 2.2012x; 2.2012x over previous
//
#include <hip/hip_runtime.h>
#include <hip/hip_bf16.h>

#define Hh 50

typedef __attribute__((ext_vector_type(8))) short bf16x8;
typedef __attribute__((ext_vector_type(4))) float f32x4;
typedef __attribute__((ext_vector_type(16))) float f32x16;

static __device__ __forceinline__ short b16(float x) {
    return __builtin_bit_cast(short, __float2bfloat16(x));
}
// convert 8 contiguous f32 to a bf16x8 MFMA fragment
static __device__ __forceinline__ bf16x8 cvt8(const float* p) {
    f32x4 a = *(const f32x4*)p;
    f32x4 b = *(const f32x4*)(p + 4);
    bf16x8 r;
    r[0] = b16(a[0]); r[1] = b16(a[1]); r[2] = b16(a[2]); r[3] = b16(a[3]);
    r[4] = b16(b[0]); r[5] = b16(b[1]); r[6] = b16(b[2]); r[7] = b16(b[3]);
    return r;
}

// -------- Kernel 0: pack wh_w into per-fragment bf16 layout for 32x32x16 B-operand --------
// whpk[((nt*16+ks)*64 + l)*8 + j] = bf16(wh_w[col*256 + k]),
//   col = nt*32 + (l&31), k = ks*16 + (l>>5)*8 + j.
// Each wave's B-frag load becomes one contiguous 1 KB block.
__global__ __launch_bounds__(256) void k_prep(const float* __restrict__ w,
                                              short* __restrict__ o) {
    int t = (int)blockIdx.x * 256 + threadIdx.x;   // 0..8191
    int nt = t >> 10;
    int ks = (t >> 6) & 15;
    int l  = t & 63;
    int col = nt * 32 + (l & 31);
    int k   = ks * 16 + (l >> 5) * 8;
    bf16x8 v = cvt8(w + (size_t)col * 256 + k);
    *(bf16x8*)(o + (size_t)t * 8) = v;
}

// ---------------- Kernel 1: wc_out[4096][256] (f32) = cur @ wc_w^T + wc_b ----------------
__global__ __launch_bounds__(64) void k_wc(const float* __restrict__ cur,
                                           const float* __restrict__ wcw,
                                           const float* __restrict__ wcb,
                                           float* __restrict__ out) {
    int l = threadIdx.x;
    int m0 = (int)(blockIdx.x >> 2) * 16;
    int ntb = (int)(blockIdx.x & 3) * 4;
    int lk = (l >> 4) * 8;

    bf16x8 Af[8];
#pragma unroll
    for (int k = 0; k < 8; k++)
        Af[k] = cvt8(cur + (size_t)(m0 + (l & 15)) * 256 + k * 32 + lk);

#pragma unroll
    for (int nt = 0; nt < 4; nt++) {
        int col = (ntb + nt) * 16 + (l & 15);
        f32x4 a = {0.f, 0.f, 0.f, 0.f};
#pragma unroll
        for (int k = 0; k < 8; k++) {
            bf16x8 Bf = cvt8(wcw + (size_t)col * 256 + k * 32 + lk);
            a = __builtin_amdgcn_mfma_f32_16x16x32_bf16(Af[k], Bf, a, 0, 0, 0);
        }
        float bias = wcb[col];
        int row = m0 + (l >> 4) * 4;
#pragma unroll
        for (int r = 0; r < 4; r++)
            out[(size_t)(row + r) * 256 + col] = a[r] + bias;
    }
}

// ---------------- Kernel 2: fused wh GEMM (32x32x16) + sigmoid + qt dot + alpha*hist ----
// Block = one (b, s): 256 thr = 4 waves. 64 hist rows in LDS (50 real + 14 zero-pad),
// 4-bit XOR swizzle. Wave w: panel p=w&1 (rows 32p..32p+31, Af[16]=64 VGPR resident,
// full K), nt-half nh=w>>1 (cols nh*128..+127 in 4 nt-tiles of 32).
// B-frag streamed from packed whpk (contiguous 1 KB per load), transient registers only.
// VGPR ~110 -> no spill at the 128 cap; LDS 35.5 KB -> 4 blocks/CU = 4 waves/SIMD.
__global__ __launch_bounds__(256, 4)
void k_main(const float* __restrict__ hist,
            const float* __restrict__ wc_ws,
            const short* __restrict__ whpk,
            const float* __restrict__ whb,
            const float* __restrict__ qtw,
            const float* __restrict__ qtb,
            float* __restrict__ hsum_ws) {
    __shared__ __align__(16) char histA[64 * 512];   // swizzled bf16 [row][256]
    __shared__ float wcrow[256];                     // wc_out[b,s,:] + wh_b
    __shared__ float qtl[256];
    __shared__ float alphaP[4][32];
    __shared__ float alphaF[64];

    int tid = threadIdx.x;
    int l = tid & 63;
    int w = tid >> 6;
    int b = (int)(blockIdx.x >> 9);
    int s = (int)(blockIdx.x & 511);

    // stage 50 hist rows (f32 -> bf16) into swizzled LDS
    for (int c = tid; c < 1600; c += 256) {
        int r = c >> 5, g = c & 31;
        bf16x8 v = cvt8(hist + ((size_t)(b * Hh + r) * 512 + s) * 256 + g * 8);
        *(bf16x8*)(&histA[r * 512 + ((g ^ (r & 15)) << 4)]) = v;
    }
    // zero pad rows 50..63
    if (tid < 448) {
        int r = 50 + (tid >> 5), g = tid & 31;
        *(f32x4*)(&histA[r * 512 + ((g ^ (r & 15)) << 4)]) = (f32x4){0.f, 0.f, 0.f, 0.f};
    }
    wcrow[tid] = wc_ws[(size_t)(b * 512 + s) * 256 + tid] + whb[tid];
    qtl[tid] = qtw[tid];
    __syncthreads();

    int p = w & 1, nh = w >> 1;

    // A fragments: rows p*32..p*32+31, all K resident (64 VGPR)
    bf16x8 Af[16];
    {
        int r = p * 32 + (l & 31);
#pragma unroll
        for (int ks = 0; ks < 16; ks++) {
            int g = ks * 2 + (l >> 5);
            Af[ks] = *(const bf16x8*)(&histA[r * 512 + ((g ^ (r & 15)) << 4)]);
        }
    }

    float pal[16];
#pragma unroll
    for (int i = 0; i < 16; i++) pal[i] = 0.f;

    const short* wq = whpk + (size_t)l * 8;
#pragma unroll 1
    for (int nt = nh * 4; nt < nh * 4 + 4; nt++) {
        f32x16 acc;
#pragma unroll
        for (int i = 0; i < 16; i++) acc[i] = 0.f;
        // 2-deep software pipeline on the B stream (keeps <=2 frags in flight)
        bf16x8 bc = *(const bf16x8*)(wq + (size_t)(nt * 16) * 512);
#pragma unroll
        for (int ks = 0; ks < 16; ks++) {
            bf16x8 bn;
            if (ks < 15) bn = *(const bf16x8*)(wq + (size_t)(nt * 16 + ks + 1) * 512);
            acc = __builtin_amdgcn_mfma_f32_32x32x16_bf16(Af[ks], bc, acc, 0, 0, 0);
            bc = bn;
        }
        int col = nt * 32 + (l & 31);
        float qv = qtl[col], wb = wcrow[col];
#pragma unroll
        for (int r = 0; r < 16; r++) {
            float v = acc[r] + wb;
            float sg = __builtin_amdgcn_rcpf(1.0f + __expf(-v));
            pal[r] += qv * sg;
        }
    }

    // reduce pal over the 32 lanes sharing each row-set (cols), write per-wave partials
#pragma unroll
    for (int r = 0; r < 16; r++) {
        float v = pal[r];
        v += __shfl_xor(v, 1);
        v += __shfl_xor(v, 2);
        v += __shfl_xor(v, 4);
        v += __shfl_xor(v, 8);
        v += __shfl_xor(v, 16);
        if ((l & 31) == 0) {
            int rowIn = (r & 3) + 8 * (r >> 2) + 4 * (l >> 5);
            alphaP[w][rowIn] = v;
        }
    }
    __syncthreads();
    if (tid < Hh) {
        int pp = tid >> 5, ri = tid & 31;
        alphaF[tid] = qtb[0] + alphaP[pp][ri] + alphaP[2 + pp][ri];
    }
    __syncthreads();

    // history_sum: thread = one output column
    {
        int d = tid;
        float a = 0.f;
#pragma unroll 2
        for (int h = 0; h < Hh; h++) {
            int g = (d >> 3) ^ (h & 15);
            unsigned short u = *(const unsigned short*)(&histA[h * 512 + (g << 4) + (d & 7) * 2]);
            unsigned int x = ((unsigned int)u) << 16;
            a += alphaF[h] * __builtin_bit_cast(float, x);
        }
        hsum_ws[(size_t)(b * 512 + s) * 256 + d] = a;
    }
}

// ---------------- Kernel 3: out[4096][128] (f32) = [cur, hsum] @ wf_w^T + wf_b ----------------
__global__ __launch_bounds__(64) void k_wf(const float* __restrict__ cur,
                                           const float* __restrict__ hsum,
                                           const float* __restrict__ wfw,
                                           const float* __restrict__ wfb,
                                           float* __restrict__ out) {
    int l = threadIdx.x;
    int m0 = (int)(blockIdx.x >> 1) * 16;
    int ntb = (int)(blockIdx.x & 1) * 4;
    int lk = (l >> 4) * 8;

    f32x4 acc[4];
#pragma unroll
    for (int nt = 0; nt < 4; nt++) acc[nt] = (f32x4){0.f, 0.f, 0.f, 0.f};

#pragma unroll
    for (int k = 0; k < 16; k++) {
        int row = m0 + (l & 15);
        bf16x8 Af;
        if (k < 8)
            Af = cvt8(cur + (size_t)row * 256 + k * 32 + lk);
        else
            Af = cvt8(hsum + (size_t)row * 256 + (k - 8) * 32 + lk);
#pragma unroll
        for (int nt = 0; nt < 4; nt++) {
            int col = (ntb + nt) * 16 + (l & 15);
            bf16x8 Bf = cvt8(wfw + (size_t)col * 512 + k * 32 + lk);
            acc[nt] = __builtin_amdgcn_mfma_f32_16x16x32_bf16(Af, Bf, acc[nt], 0, 0, 0);
        }
    }
#pragma unroll
    for (int nt = 0; nt < 4; nt++) {
        int col = (ntb + nt) * 16 + (l & 15);
        float bias = wfb[col];
        int row = m0 + (l >> 4) * 4;
#pragma unroll
        for (int r = 0; r < 4; r++)
            out[(size_t)(row + r) * 128 + col] = acc[nt][r] + bias;
    }
}

extern "C" void kernel_launch(void* const* d_in, const int* in_sizes, int n_in,
                              void* d_out, int out_size, void* d_ws, size_t ws_size,
                              hipStream_t stream) {
    const float* hist = (const float*)d_in[0];
    const float* cur  = (const float*)d_in[1];
    const float* wc_w = (const float*)d_in[2];
    const float* wc_b = (const float*)d_in[3];
    const float* wh_w = (const float*)d_in[4];
    const float* wh_b = (const float*)d_in[5];
    const float* qt_w = (const float*)d_in[6];
    const float* qt_b = (const float*)d_in[7];
    const float* wf_w = (const float*)d_in[8];
    const float* wf_b = (const float*)d_in[9];

    float* wc_ws = (float*)d_ws;                                   // 4 MB
    float* hsum  = (float*)((char*)d_ws + ((size_t)4 << 20));      // 4 MB
    short* whpk  = (short*)((char*)d_ws + ((size_t)8 << 20));      // 128 KB packed wh_w

    k_prep<<<32, 256, 0, stream>>>(wh_w, whpk);
    k_wc<<<1024, 64, 0, stream>>>(cur, wc_w, wc_b, wc_ws);
    k_main<<<4096, 256, 0, stream>>>(hist, wc_ws, whpk, wh_b, qt_w, qt_b, hsum);
    k_wf<<<512, 64, 0, stream>>>(cur, hsum, wf_w, wf_b, (float*)d_out);
}

// Round 8
// 130.497 us; speedup vs baseline: 2.2836x; 1.0374x over previous
//
#include <hip/hip_runtime.h>
#include <hip/hip_bf16.h>

#define Hh 50

typedef __attribute__((ext_vector_type(8))) short bf16x8;
typedef __attribute__((ext_vector_type(4))) float f32x4;
typedef __attribute__((ext_vector_type(16))) float f32x16;

static __device__ __forceinline__ short b16(float x) {
    return __builtin_bit_cast(short, __float2bfloat16(x));
}
// convert 8 contiguous f32 to a bf16x8 MFMA fragment
static __device__ __forceinline__ bf16x8 cvt8(const float* p) {
    f32x4 a = *(const f32x4*)p;
    f32x4 b = *(const f32x4*)(p + 4);
    bf16x8 r;
    r[0] = b16(a[0]); r[1] = b16(a[1]); r[2] = b16(a[2]); r[3] = b16(a[3]);
    r[4] = b16(b[0]); r[5] = b16(b[1]); r[6] = b16(b[2]); r[7] = b16(b[3]);
    return r;
}

// -------- Kernel 0: pack wh_w into per-fragment bf16 layout for 32x32x16 B-operand --------
// whpk[((nt*16+ks)*64 + l)*8 + j] = bf16(wh_w[col*256 + k]),
//   col = nt*32 + (l&31), k = ks*16 + (l>>5)*8 + j.
__global__ __launch_bounds__(256) void k_prep(const float* __restrict__ w,
                                              short* __restrict__ o) {
    int t = (int)blockIdx.x * 256 + threadIdx.x;   // 0..8191
    int nt = t >> 10;
    int ks = (t >> 6) & 15;
    int l  = t & 63;
    int col = nt * 32 + (l & 31);
    int k   = ks * 16 + (l >> 5) * 8;
    bf16x8 v = cvt8(w + (size_t)col * 256 + k);
    *(bf16x8*)(o + (size_t)t * 8) = v;
}

// ---------------- Kernel 1: wc_out[4096][256] (f32) = cur @ wc_w^T + wc_b ----------------
__global__ __launch_bounds__(64) void k_wc(const float* __restrict__ cur,
                                           const float* __restrict__ wcw,
                                           const float* __restrict__ wcb,
                                           float* __restrict__ out) {
    int l = threadIdx.x;
    int m0 = (int)(blockIdx.x >> 2) * 16;
    int ntb = (int)(blockIdx.x & 3) * 4;
    int lk = (l >> 4) * 8;

    bf16x8 Af[8];
#pragma unroll
    for (int k = 0; k < 8; k++)
        Af[k] = cvt8(cur + (size_t)(m0 + (l & 15)) * 256 + k * 32 + lk);

#pragma unroll
    for (int nt = 0; nt < 4; nt++) {
        int col = (ntb + nt) * 16 + (l & 15);
        f32x4 a = {0.f, 0.f, 0.f, 0.f};
#pragma unroll
        for (int k = 0; k < 8; k++) {
            bf16x8 Bf = cvt8(wcw + (size_t)col * 256 + k * 32 + lk);
            a = __builtin_amdgcn_mfma_f32_16x16x32_bf16(Af[k], Bf, a, 0, 0, 0);
        }
        float bias = wcb[col];
        int row = m0 + (l >> 4) * 4;
#pragma unroll
        for (int r = 0; r < 4; r++)
            out[(size_t)(row + r) * 256 + col] = a[r] + bias;
    }
}

// ---------------- Kernel 2: fused wh GEMM (32x32x16) + sigmoid + qt dot + alpha*hist ----
// Block = one (b, s): 256 thr = 4 waves. Wave w: panel p=w&1 (rows 32p..+31, Af[16]
// resident), nt-half nh=w>>1. B streamed from packed whpk through a 6-deep rotating
// register pipeline across a flattened fully-unrolled 64-step (nt x ks) loop, so
// ~6 L2 loads stay in flight per wave (incl. across sigmoid epilogues).
__global__ __launch_bounds__(256, 4)
void k_main(const float* __restrict__ hist,
            const float* __restrict__ wc_ws,
            const short* __restrict__ whpk,
            const float* __restrict__ whb,
            const float* __restrict__ qtw,
            const float* __restrict__ qtb,
            float* __restrict__ hsum_ws) {
    __shared__ __align__(16) char histA[64 * 512];   // swizzled bf16 [row][256]
    __shared__ float wcrow[256];                     // wc_out[b,s,:] + wh_b
    __shared__ float qtl[256];
    __shared__ float alphaP[4][32];
    __shared__ float alphaF[64];

    int tid = threadIdx.x;
    int l = tid & 63;
    int w = tid >> 6;
    int b = (int)(blockIdx.x >> 9);
    int s = (int)(blockIdx.x & 511);

    // stage 50 hist rows (f32 -> bf16) into swizzled LDS
    for (int c = tid; c < 1600; c += 256) {
        int r = c >> 5, g = c & 31;
        bf16x8 v = cvt8(hist + ((size_t)(b * Hh + r) * 512 + s) * 256 + g * 8);
        *(bf16x8*)(&histA[r * 512 + ((g ^ (r & 15)) << 4)]) = v;
    }
    // zero pad rows 50..63
    if (tid < 448) {
        int r = 50 + (tid >> 5), g = tid & 31;
        *(f32x4*)(&histA[r * 512 + ((g ^ (r & 15)) << 4)]) = (f32x4){0.f, 0.f, 0.f, 0.f};
    }
    wcrow[tid] = wc_ws[(size_t)(b * 512 + s) * 256 + tid] + whb[tid];
    qtl[tid] = qtw[tid];
    __syncthreads();

    int p = w & 1, nh = w >> 1;

    // A fragments: rows p*32..p*32+31, all K resident (64 VGPR)
    bf16x8 Af[16];
    {
        int r = p * 32 + (l & 31);
#pragma unroll
        for (int ks = 0; ks < 16; ks++) {
            int g = ks * 2 + (l >> 5);
            Af[ks] = *(const bf16x8*)(&histA[r * 512 + ((g ^ (r & 15)) << 4)]);
        }
    }

    float pal[16];
#pragma unroll
    for (int i = 0; i < 16; i++) pal[i] = 0.f;

    const short* wq = whpk + (size_t)l * 8;   // frag f at wq + f*512 (shorts)

    // 6-deep rotating B prefetch over the flattened 64-step loop
    bf16x8 Bq[6];
#pragma unroll
    for (int j = 0; j < 6; j++)
        Bq[j] = *(const bf16x8*)(wq + (size_t)(nh * 64 + j) * 512);

    f32x16 acc;
#pragma unroll
    for (int step = 0; step < 64; step++) {
        int ks = step & 15;
        if (ks == 0) {
#pragma unroll
            for (int i = 0; i < 16; i++) acc[i] = 0.f;
        }
        acc = __builtin_amdgcn_mfma_f32_32x32x16_bf16(Af[ks], Bq[step % 6], acc, 0, 0, 0);
        if (step + 6 < 64)
            Bq[step % 6] = *(const bf16x8*)(wq + (size_t)(nh * 64 + step + 6) * 512);
        if (ks == 15) {
            int nt = nh * 4 + (step >> 4);
            int col = nt * 32 + (l & 31);
            float qv = qtl[col], wb = wcrow[col];
#pragma unroll
            for (int r = 0; r < 16; r++) {
                float v = acc[r] + wb;
                float sg = __builtin_amdgcn_rcpf(1.0f + __expf(-v));
                pal[r] += qv * sg;
            }
        }
    }

    // reduce pal over the 32 lanes sharing each row-set (cols), write per-wave partials
#pragma unroll
    for (int r = 0; r < 16; r++) {
        float v = pal[r];
        v += __shfl_xor(v, 1);
        v += __shfl_xor(v, 2);
        v += __shfl_xor(v, 4);
        v += __shfl_xor(v, 8);
        v += __shfl_xor(v, 16);
        if ((l & 31) == 0) {
            int rowIn = (r & 3) + 8 * (r >> 2) + 4 * (l >> 5);
            alphaP[w][rowIn] = v;
        }
    }
    __syncthreads();
    if (tid < Hh) {
        int pp = tid >> 5, ri = tid & 31;
        alphaF[tid] = qtb[0] + alphaP[pp][ri] + alphaP[2 + pp][ri];
    }
    __syncthreads();

    // history_sum: thread = one output column
    {
        int d = tid;
        float a = 0.f;
#pragma unroll 2
        for (int h = 0; h < Hh; h++) {
            int g = (d >> 3) ^ (h & 15);
            unsigned short u = *(const unsigned short*)(&histA[h * 512 + (g << 4) + (d & 7) * 2]);
            unsigned int x = ((unsigned int)u) << 16;
            a += alphaF[h] * __builtin_bit_cast(float, x);
        }
        hsum_ws[(size_t)(b * 512 + s) * 256 + d] = a;
    }
}

// ---------------- Kernel 3: out[4096][128] (f32) = [cur, hsum] @ wf_w^T + wf_b ----------------
__global__ __launch_bounds__(64) void k_wf(const float* __restrict__ cur,
                                           const float* __restrict__ hsum,
                                           const float* __restrict__ wfw,
                                           const float* __restrict__ wfb,
                                           float* __restrict__ out) {
    int l = threadIdx.x;
    int m0 = (int)(blockIdx.x >> 1) * 16;
    int ntb = (int)(blockIdx.x & 1) * 4;
    int lk = (l >> 4) * 8;

    f32x4 acc[4];
#pragma unroll
    for (int nt = 0; nt < 4; nt++) acc[nt] = (f32x4){0.f, 0.f, 0.f, 0.f};

#pragma unroll
    for (int k = 0; k < 16; k++) {
        int row = m0 + (l & 15);
        bf16x8 Af;
        if (k < 8)
            Af = cvt8(cur + (size_t)row * 256 + k * 32 + lk);
        else
            Af = cvt8(hsum + (size_t)row * 256 + (k - 8) * 32 + lk);
#pragma unroll
        for (int nt = 0; nt < 4; nt++) {
            int col = (ntb + nt) * 16 + (l & 15);
            bf16x8 Bf = cvt8(wfw + (size_t)col * 512 + k * 32 + lk);
            acc[nt] = __builtin_amdgcn_mfma_f32_16x16x32_bf16(Af, Bf, acc[nt], 0, 0, 0);
        }
    }
#pragma unroll
    for (int nt = 0; nt < 4; nt++) {
        int col = (ntb + nt) * 16 + (l & 15);
        float bias = wfb[col];
        int row = m0 + (l >> 4) * 4;
#pragma unroll
        for (int r = 0; r < 4; r++)
            out[(size_t)(row + r) * 128 + col] = acc[nt][r] + bias;
    }
}

extern "C" void kernel_launch(void* const* d_in, const int* in_sizes, int n_in,
                              void* d_out, int out_size, void* d_ws, size_t ws_size,
                              hipStream_t stream) {
    const float* hist = (const float*)d_in[0];
    const float* cur  = (const float*)d_in[1];
    const float* wc_w = (const float*)d_in[2];
    const float* wc_b = (const float*)d_in[3];
    const float* wh_w = (const float*)d_in[4];
    const float* wh_b = (const float*)d_in[5];
    const float* qt_w = (const float*)d_in[6];
    const float* qt_b = (const float*)d_in[7];
    const float* wf_w = (const float*)d_in[8];
    const float* wf_b = (const float*)d_in[9];

    float* wc_ws = (float*)d_ws;                                   // 4 MB
    float* hsum  = (float*)((char*)d_ws + ((size_t)4 << 20));      // 4 MB
    short* whpk  = (short*)((char*)d_ws + ((size_t)8 << 20));      // 128 KB packed wh_w

    k_prep<<<32, 256, 0, stream>>>(wh_w, whpk);
    k_wc<<<1024, 64, 0, stream>>>(cur, wc_w, wc_b, wc_ws);
    k_main<<<4096, 256, 0, stream>>>(hist, wc_ws, whpk, wh_b, qt_w, qt_b, hsum);
    k_wf<<<512, 64, 0, stream>>>(cur, hsum, wf_w, wf_b, (float*)d_out);
}